// Round 1
// 396.610 us; speedup vs baseline: 1.1127x; 1.1127x over previous
//
#include <hip/hip_runtime.h>
#include <hip/hip_bf16.h>

typedef __hip_bfloat16 bf16;
typedef __attribute__((ext_vector_type(8))) short short8;
typedef __attribute__((ext_vector_type(4))) float floatx4;
typedef __attribute__((ext_vector_type(4))) short shortx4;

static constexpr int BATCH = 4;
static constexpr int CH    = 512;   // C
static constexpr int SEQ   = 4096;  // H*W
static constexpr int DM    = 512;   // model dim

__device__ __forceinline__ void gload16(const void* g, void* l) {
  __builtin_amdgcn_global_load_lds(
      (const __attribute__((address_space(1))) unsigned int*)g,
      (__attribute__((address_space(3))) unsigned int*)l,
      16, 0, 0);
}

// ---------------------------------------------------------------------------
// Weight fp32 -> bf16 conversion (4 matrices of 512x512)
// ---------------------------------------------------------------------------
__global__ __launch_bounds__(256) void cvt_weights(
    const float* __restrict__ w0, const float* __restrict__ w1,
    const float* __restrict__ w2, const float* __restrict__ w3,
    bf16* __restrict__ out) {
  const float* src = (blockIdx.y == 0) ? w0 : (blockIdx.y == 1) ? w1
                   : (blockIdx.y == 2) ? w2 : w3;
  int idx = blockIdx.x * 256 + threadIdx.x;
  out[(long)blockIdx.y * (DM * CH) + idx] = __float2bfloat16(src[idx]);
}

// ---------------------------------------------------------------------------
// x (b,c,s) fp32 -> xT (b,s,c) bf16, 64x64 LDS tiles
// ---------------------------------------------------------------------------
__global__ __launch_bounds__(256) void transpose_cvt(
    const float* __restrict__ x, bf16* __restrict__ xT) {
  __shared__ float tile[64][65];
  const int s0 = blockIdx.x * 64, c0 = blockIdx.y * 64;
  const float* xb = x + (long)blockIdx.z * CH * SEQ;
  bf16* xTb = xT + (long)blockIdx.z * SEQ * CH;
  const int t = threadIdx.x;
  const int sl = t & 63, cq = t >> 6;
  #pragma unroll
  for (int i = 0; i < 16; ++i) {
    int cl = cq * 16 + i;
    tile[cl][sl] = xb[(long)(c0 + cl) * SEQ + s0 + sl];
  }
  __syncthreads();
  const int cl2 = t & 63, sq = t >> 6;
  #pragma unroll
  for (int i = 0; i < 16; ++i) {
    int sl2 = sq * 16 + i;
    xTb[(long)(s0 + sl2) * CH + c0 + cl2] = __float2bfloat16(tile[cl2][sl2]);
  }
}

// ---------------------------------------------------------------------------
// Generic BT GEMM (kept for the 512-N projections): 128x128 tile, BK=32.
// MODE 0: bf16 out = acc + bias[col], C[row*ldc+col]
// MODE 1: bf16 out = acc + bias[col], transposed C[col*ldc+row]
// MODE 4: f32  out = acc + bias[col], transposed C[col*ldc+row]
// ---------------------------------------------------------------------------
template <int MODE>
__global__ __launch_bounds__(256) void gemm_bt(
    const bf16* __restrict__ A, long sAz,
    const bf16* __restrict__ B, long sBz,
    void* __restrict__ Cv, long sCz,
    const float* __restrict__ bias, float scale,
    int M, int N, int K, int ldc) {
  __shared__ bf16 At[128 * 32];
  __shared__ bf16 Bt[128 * 32];
  const int tid = threadIdx.x;
  const int z = blockIdx.z;
  const long lK = K;
  const bf16* Ab = A + (long)z * sAz + (long)blockIdx.y * 128 * lK;
  const bf16* Bb = B + (long)z * sBz + (long)blockIdx.x * 128 * lK;

  const int w = tid >> 6, lane = tid & 63;
  const int wm = (w & 1) << 6, wn = (w >> 1) << 6;
  const int l16 = lane & 15, quad = lane >> 4;

  floatx4 acc[4][4];
  #pragma unroll
  for (int i = 0; i < 4; ++i)
    #pragma unroll
    for (int j = 0; j < 4; ++j) acc[i][j] = (floatx4)(0.0f);

  const int row0 = tid >> 2;          // 0..63
  const int col0 = (tid & 3) << 3;    // 0,8,16,24 (bf16 elements)
  const int nk = K >> 5;
  for (int kt = 0; kt < nk; ++kt) {
    const bf16* Ak = Ab + (kt << 5);
    const bf16* Bk = Bb + (kt << 5);
    gload16(Ak + (long)row0 * lK + col0,        (char*)At + tid * 16);
    gload16(Ak + (long)(row0 + 64) * lK + col0, (char*)At + (tid + 256) * 16);
    gload16(Bk + (long)row0 * lK + col0,        (char*)Bt + tid * 16);
    gload16(Bk + (long)(row0 + 64) * lK + col0, (char*)Bt + (tid + 256) * 16);
    __syncthreads();
    short8 af[4], bfr[4];
    #pragma unroll
    for (int i = 0; i < 4; ++i)
      af[i] = *(const short8*)(At + (wm + i * 16 + l16) * 32 + (quad << 3));
    #pragma unroll
    for (int j = 0; j < 4; ++j)
      bfr[j] = *(const short8*)(Bt + (wn + j * 16 + l16) * 32 + (quad << 3));
    #pragma unroll
    for (int i = 0; i < 4; ++i)
      #pragma unroll
      for (int j = 0; j < 4; ++j)
        acc[i][j] = __builtin_amdgcn_mfma_f32_16x16x32_bf16(af[i], bfr[j],
                                                            acc[i][j], 0, 0, 0);
    __syncthreads();
  }

  const int mbase = blockIdx.y * 128 + wm + quad * 4;
  const int nbase = blockIdx.x * 128 + wn + l16;
  #pragma unroll
  for (int i = 0; i < 4; ++i) {
    const int row = mbase + i * 16;
    #pragma unroll
    for (int j = 0; j < 4; ++j) {
      const int col = nbase + j * 16;
      floatx4 v = acc[i][j];
      if constexpr (MODE == 0) {
        bf16* C = (bf16*)Cv + (long)z * sCz;
        const float bb = bias[col];
        #pragma unroll
        for (int r = 0; r < 4; ++r)
          C[(long)(row + r) * ldc + col] = __float2bfloat16(v[r] + bb);
      } else if constexpr (MODE == 1) {
        bf16* C = (bf16*)Cv + (long)z * sCz;
        const float bb = bias[col];
        alignas(8) bf16 tmp[4];
        #pragma unroll
        for (int r = 0; r < 4; ++r) tmp[r] = __float2bfloat16(v[r] + bb);
        *(shortx4*)(C + (long)col * ldc + row) = *(const shortx4*)tmp;
      } else {  // MODE 4
        float* C = (float*)Cv + (long)z * sCz;
        const float bb = bias[col];
        floatx4 o_;
        #pragma unroll
        for (int r = 0; r < 4; ++r) o_[r] = v[r] + bb;
        *(floatx4*)(C + (long)col * ldc + row) = o_;
      }
    }
  }
}

// ---------------------------------------------------------------------------
// Big BT GEMM: 256 x (NREP*64) tile, BK=64, 512 threads = 8 waves (2M x 4N).
// Per-wave output: 128 x (NREP*16).  C[m,n] = scale * sum_k A[m,k]*B[n,k].
// Techniques: T1 XCD swizzle, T2 LDS XOR-swizzle (slot ^ (row&7), 128B rows),
// phase-interleaved MFMA with raw s_barrier, one vmcnt(0) drain per K-tile
// (staging issued 2-3 phases earlier so the drain finds loads landed),
// T5 setprio around each MFMA cluster.
// Requires: M % 256 == 0, N % (NREP*64) == 0, K % 64 == 0, K >= 128.
// ---------------------------------------------------------------------------
template <int NREP>
__global__ __launch_bounds__(512, 2) void gemm_big(
    const bf16* __restrict__ A, long sAz,
    const bf16* __restrict__ B, long sBz,
    bf16* __restrict__ C, long sCz,
    float scale, int K, int ldc) {
  constexpr int BN = NREP * 64;     // 256 or 128
  constexpr int NJ = NREP / 2;      // 2 or 1
  constexpr int BROUNDS = BN / 64;  // B staging rounds: 4 or 2
  __shared__ __align__(16) bf16 As[2][256 * 64];
  __shared__ __align__(16) bf16 Bs[2][BN * 64];

  // --- T1: bijective XCD-aware block swizzle ---
  int id = blockIdx.x + gridDim.x * (blockIdx.y + gridDim.y * blockIdx.z);
  int nwg = gridDim.x * gridDim.y * gridDim.z;
  int sid = ((nwg & 7) == 0) ? ((id & 7) * (nwg >> 3) + (id >> 3)) : id;
  const int bx = sid % gridDim.x;
  const int by = (sid / gridDim.x) % gridDim.y;
  const int bz = sid / (gridDim.x * gridDim.y);

  const int tid = threadIdx.x;
  const long lK = K;
  const bf16* Ab = A + (long)bz * sAz + (long)by * 256 * lK;
  const bf16* Bb = B + (long)bz * sBz + (long)bx * BN * lK;

  const int w = tid >> 6, lane = tid & 63;
  const int wr = w >> 2, wc = w & 3;          // 2 x 4 wave grid
  const int l16 = lane & 15, quad = lane >> 4;

  // staging coords: thread -> (row srow within 64-row round, 16B slot sp)
  const int srow = tid >> 3;                  // 0..63
  const int sp = tid & 7;                     // physical slot
  // physical slot sp must hold logical slot sp ^ (row & 7); row&7 == srow&7
  const int slog = (sp ^ (srow & 7)) << 3;    // element offset in source row

  // fragment read slots (T2 swizzle): logical slot = kk*4+quad, row&7 = l16&7
  const int pA0 = (quad ^ (l16 & 7)) << 3;    // kk = 0
  const int pA1 = pA0 ^ 32;                   // kk = 1 (slot ^ 4)

  auto stageA = [&](int buf, int kt) {
    const bf16* s = Ab + (long)kt * 64 + (long)srow * lK + slog;
    char* d = (char*)(&As[buf][0]) + tid * 16;
    #pragma unroll
    for (int r = 0; r < 4; ++r)
      gload16(s + (long)(r * 64) * lK, d + r * 8192);
  };
  auto stageB = [&](int buf, int kt) {
    const bf16* s = Bb + (long)kt * 64 + (long)srow * lK + slog;
    char* d = (char*)(&Bs[buf][0]) + tid * 16;
    #pragma unroll
    for (int r = 0; r < BROUNDS; ++r)
      gload16(s + (long)(r * 64) * lK, d + r * 8192);
  };

  floatx4 acc[8][NREP];
  #pragma unroll
  for (int m = 0; m < 8; ++m)
    #pragma unroll
    for (int n = 0; n < NREP; ++n) acc[m][n] = (floatx4)(0.0f);

  // prologue: tile 0 -> buf 0 (no cover available; one-time cost)
  stageA(0, 0);
  stageB(0, 0);
  asm volatile("s_waitcnt vmcnt(0)" ::: "memory");
  __builtin_amdgcn_s_barrier();

  const int nk = K >> 6;
  int cur = 0;
  for (int t = 0; t < nk; ++t) {
    const bf16* __restrict__ Al = &As[cur][0];
    const bf16* __restrict__ Bl = &Bs[cur][0];
    const bool last = (t == nk - 1);
    short8 a0[4], a1[4], b0[NJ], b1[NJ];
    #pragma unroll
    for (int qm = 0; qm < 2; ++qm) {
      // A fragments for this row-quadrant (8 ds_read_b128, conflict-free)
      #pragma unroll
      for (int i = 0; i < 4; ++i) {
        const int ar = wr * 128 + qm * 64 + i * 16 + l16;
        const bf16* pa = Al + ar * 64;
        a0[i] = *(const short8*)(pa + pA0);
        a1[i] = *(const short8*)(pa + pA1);
      }
      #pragma unroll
      for (int qn = 0; qn < 2; ++qn) {
        // B fragments for this col-quadrant
        #pragma unroll
        for (int j = 0; j < NJ; ++j) {
          const int br = wc * (NREP * 16) + qn * (NJ * 16) + j * 16 + l16;
          const bf16* pb = Bl + br * 64;
          b0[j] = *(const short8*)(pb + pA0);
          b1[j] = *(const short8*)(pb + pA1);
        }
        // issue next-tile staging early (phases 0,1) -> ~2-3 phases of cover
        if (!last) {
          if (qm == 0 && qn == 0) stageA(cur ^ 1, t + 1);
          if (qm == 0 && qn == 1) stageB(cur ^ 1, t + 1);
        }
        __builtin_amdgcn_s_barrier();
        __builtin_amdgcn_s_setprio(1);
        #pragma unroll
        for (int i = 0; i < 4; ++i)
          #pragma unroll
          for (int j = 0; j < NJ; ++j) {
            const int m = qm * 4 + i, n = qn * NJ + j;
            acc[m][n] = __builtin_amdgcn_mfma_f32_16x16x32_bf16(
                a0[i], b0[j], acc[m][n], 0, 0, 0);
            acc[m][n] = __builtin_amdgcn_mfma_f32_16x16x32_bf16(
                a1[i], b1[j], acc[m][n], 0, 0, 0);
          }
        __builtin_amdgcn_s_setprio(0);
        if (qm == 1 && qn == 1) {
          // tile boundary: per-wave drain (loads issued >=2 phases ago),
          // then block-wide barrier -> buffer swap is safe
          asm volatile("s_waitcnt vmcnt(0)" ::: "memory");
        }
        __builtin_amdgcn_s_barrier();
      }
    }
    cur ^= 1;
  }

  // epilogue: scale + bf16 store, row-major
  bf16* Cb = C + (long)bz * sCz;
  const int rbase = by * 256 + wr * 128 + quad * 4;
  const int cbase = bx * BN + wc * (NREP * 16) + l16;
  #pragma unroll
  for (int m = 0; m < 8; ++m) {
    const int row = rbase + m * 16;
    #pragma unroll
    for (int n = 0; n < NREP; ++n) {
      const int col = cbase + n * 16;
      floatx4 v = acc[m][n];
      #pragma unroll
      for (int r = 0; r < 4; ++r)
        Cb[(long)(row + r) * ldc + col] = __float2bfloat16(v[r] * scale);
    }
  }
}

// ---------------------------------------------------------------------------
// In-place row softmax over bf16 rows of length 4096. One block per row.
// ---------------------------------------------------------------------------
__global__ __launch_bounds__(256) void softmax_rows(bf16* __restrict__ sim) {
  bf16* p = sim + (long)blockIdx.y * ((long)SEQ * SEQ) + (long)blockIdx.x * SEQ;
  uint4* p4 = (uint4*)p;
  const int t = threadIdx.x;
  union U { uint4 u; ushort h[8]; } d[2];
  d[0].u = p4[t];
  d[1].u = p4[t + 256];
  float v[16];
  float mx = -3.0e38f;
  #pragma unroll
  for (int i = 0; i < 16; ++i) {
    v[i] = __uint_as_float(((unsigned)d[i >> 3].h[i & 7]) << 16);
    mx = fmaxf(mx, v[i]);
  }
  #pragma unroll
  for (int o = 32; o > 0; o >>= 1) mx = fmaxf(mx, __shfl_xor(mx, o));
  __shared__ float redmax[4], redsum[4];
  if ((t & 63) == 0) redmax[t >> 6] = mx;
  __syncthreads();
  mx = fmaxf(fmaxf(redmax[0], redmax[1]), fmaxf(redmax[2], redmax[3]));
  float sum = 0.f;
  #pragma unroll
  for (int i = 0; i < 16; ++i) {
    v[i] = __expf(v[i] - mx);
    sum += v[i];
  }
  #pragma unroll
  for (int o = 32; o > 0; o >>= 1) sum += __shfl_xor(sum, o);
  if ((t & 63) == 0) redsum[t >> 6] = sum;
  __syncthreads();
  sum = redsum[0] + redsum[1] + redsum[2] + redsum[3];
  const float inv = 1.0f / sum;
  union Hb { __hip_bfloat16 h; ushort u; };
  #pragma unroll
  for (int i = 0; i < 16; ++i) {
    Hb hb;
    hb.h = __float2bfloat16(v[i] * inv);
    d[i >> 3].h[i & 7] = hb.u;
  }
  p4[t] = d[0].u;
  p4[t + 256] = d[1].u;
}

// ---------------------------------------------------------------------------
extern "C" void kernel_launch(void* const* d_in, const int* in_sizes, int n_in,
                              void* d_out, int out_size, void* d_ws,
                              size_t ws_size, hipStream_t stream) {
  const float* q  = (const float*)d_in[0];
  const float* Wq = (const float*)d_in[1];
  const float* bq = (const float*)d_in[2];
  const float* Wk = (const float*)d_in[3];
  const float* bk = (const float*)d_in[4];
  const float* Wv = (const float*)d_in[5];
  const float* bv = (const float*)d_in[6];
  const float* Wo = (const float*)d_in[7];
  const float* bo = (const float*)d_in[8];
  float* out = (float*)d_out;

  bf16* ws = (bf16*)d_ws;
  const long WSZ = (long)DM * CH;         // 262144 elems per weight matrix
  const long XSZ = (long)SEQ * CH;        // 2097152 elems per batch
  const long SSZ = (long)SEQ * SEQ;       // 16777216 elems per batch
  bf16* Wqb = ws;
  bf16* Wkb = Wqb + WSZ;
  bf16* Wvb = Wqb + 2 * WSZ;
  bf16* Wob = Wqb + 3 * WSZ;
  bf16* xT  = Wqb + 4 * WSZ;
  bf16* Qb  = xT + BATCH * XSZ;
  bf16* Kb  = Qb + BATCH * XSZ;
  bf16* Vt  = Kb + BATCH * XSZ;   // (b, d, s) layout
  bf16* Ob  = Vt + BATCH * XSZ;
  bf16* Sim = Ob + BATCH * XSZ;   // (b, s, t) bf16, softmaxed in place

  cvt_weights<<<dim3(WSZ / 256, 4), 256, 0, stream>>>(Wq, Wk, Wv, Wo, ws);
  transpose_cvt<<<dim3(SEQ / 64, CH / 64, BATCH), 256, 0, stream>>>(q, xT);

  // Q = xT * Wq^T + bq  (4096x512x512), bf16 out
  gemm_bt<0><<<dim3(4, 32, BATCH), 256, 0, stream>>>(
      xT, XSZ, Wqb, 0, Qb, XSZ, bq, 1.f, SEQ, DM, CH, DM);
  gemm_bt<0><<<dim3(4, 32, BATCH), 256, 0, stream>>>(
      xT, XSZ, Wkb, 0, Kb, XSZ, bk, 1.f, SEQ, DM, CH, DM);
  // V stored transposed: Vt[d][s]
  gemm_bt<1><<<dim3(4, 32, BATCH), 256, 0, stream>>>(
      xT, XSZ, Wvb, 0, Vt, XSZ, bv, 1.f, SEQ, DM, CH, SEQ);
  // sim = Q*K^T * scale (4096x4096x512): 256x256 tile, 8-wave phased kernel
  gemm_big<4><<<dim3(16, 16, BATCH), 512, 0, stream>>>(
      Qb, XSZ, Kb, XSZ, Sim, SSZ, 0.04419417382415922f, CH, SEQ);
  softmax_rows<<<dim3(SEQ, BATCH), 256, 0, stream>>>(Sim);
  // o = P * V  (4096x512x4096): 256x128 tile -> 256 blocks = 1/CU
  gemm_big<2><<<dim3(4, 16, BATCH), 512, 0, stream>>>(
      Sim, SSZ, Vt, XSZ, Ob, XSZ, 1.0f, SEQ, DM);
  // y = o * Wo^T + bo, stored transposed into d_out as (b, c, s) fp32
  gemm_bt<4><<<dim3(4, 32, BATCH), 256, 0, stream>>>(
      Ob, XSZ, Wob, 0, out, XSZ, bo, 1.f, SEQ, CH, DM, SEQ);
}

// Round 2
// 382.118 us; speedup vs baseline: 1.1549x; 1.0379x over previous
//
#include <hip/hip_runtime.h>
#include <hip/hip_bf16.h>

typedef __hip_bfloat16 bf16;
typedef __attribute__((ext_vector_type(8))) short short8;
typedef __attribute__((ext_vector_type(4))) float floatx4;
typedef __attribute__((ext_vector_type(4))) short shortx4;

static constexpr int BATCH = 4;
static constexpr int CH    = 512;   // C
static constexpr int SEQ   = 4096;  // H*W
static constexpr int DM    = 512;   // model dim

__device__ __forceinline__ void gload16(const void* g, void* l) {
  __builtin_amdgcn_global_load_lds(
      (const __attribute__((address_space(1))) unsigned int*)g,
      (__attribute__((address_space(3))) unsigned int*)l,
      16, 0, 0);
}

// ---------------------------------------------------------------------------
// Weight fp32 -> bf16 conversion (4 matrices of 512x512)
// ---------------------------------------------------------------------------
__global__ __launch_bounds__(256) void cvt_weights(
    const float* __restrict__ w0, const float* __restrict__ w1,
    const float* __restrict__ w2, const float* __restrict__ w3,
    bf16* __restrict__ out) {
  const float* src = (blockIdx.y == 0) ? w0 : (blockIdx.y == 1) ? w1
                   : (blockIdx.y == 2) ? w2 : w3;
  int idx = blockIdx.x * 256 + threadIdx.x;
  out[(long)blockIdx.y * (DM * CH) + idx] = __float2bfloat16(src[idx]);
}

// ---------------------------------------------------------------------------
// x (b,c,s) fp32 -> xT (b,s,c) bf16, 64x64 LDS tiles
// ---------------------------------------------------------------------------
__global__ __launch_bounds__(256) void transpose_cvt(
    const float* __restrict__ x, bf16* __restrict__ xT) {
  __shared__ float tile[64][65];
  const int s0 = blockIdx.x * 64, c0 = blockIdx.y * 64;
  const float* xb = x + (long)blockIdx.z * CH * SEQ;
  bf16* xTb = xT + (long)blockIdx.z * SEQ * CH;
  const int t = threadIdx.x;
  const int sl = t & 63, cq = t >> 6;
  #pragma unroll
  for (int i = 0; i < 16; ++i) {
    int cl = cq * 16 + i;
    tile[cl][sl] = xb[(long)(c0 + cl) * SEQ + s0 + sl];
  }
  __syncthreads();
  const int cl2 = t & 63, sq = t >> 6;
  #pragma unroll
  for (int i = 0; i < 16; ++i) {
    int sl2 = sq * 16 + i;
    xTb[(long)(s0 + sl2) * CH + c0 + cl2] = __float2bfloat16(tile[cl2][sl2]);
  }
}

// ---------------------------------------------------------------------------
// Big BT GEMM: 256 x (NREP*64) tile, BK=64, 512 threads = 8 waves (2M x 4N).
// Per-wave output: 128 x (NREP*16).  C[m,n] = sum_k A[m,k]*B[n,k] (+epilogue).
// 4 balanced phases per K-tile: p -> (qm = p>>1, kc = p&1).
//   phase reads: 4 A-frags (qm,kc); +NREP B-frags (kc) when qm==0 (B held in
//   regs across qm=1 -> no redundant LDS reads; 24 ds_read_b128/wave/tile).
// T1 XCD swizzle, T2 LDS XOR-swizzle (16B slot ^ (row&7), 128B rows),
// raw s_barrier lockstep, T5 setprio, single vmcnt(0) drain per K-tile
// (staging issued at phases 0/1, drained at end of phase 3).
// MODE 0: bf16 out = acc + bias[col], C[row*ldc+col]
// MODE 1: bf16 out = acc + bias[col], transposed C[col*ldc+row]
// MODE 2: bf16 out = acc * scale,     C[row*ldc+col]
// MODE 4: f32  out = acc + bias[col], transposed C[col*ldc+row]
// Requires: M % 256 == 0, N % (NREP*64) == 0, K % 64 == 0, K >= 128.
// ---------------------------------------------------------------------------
template <int NREP, int MODE>
__global__ __launch_bounds__(512, 2) void gemm_big(
    const bf16* __restrict__ A, long sAz,
    const bf16* __restrict__ B, long sBz,
    void* __restrict__ Cv, long sCz,
    const float* __restrict__ bias, float scale,
    int K, int ldc) {
  constexpr int BN = NREP * 64;     // 256 or 128
  constexpr int BROUNDS = BN / 64;  // B staging rounds: 4 or 2
  __shared__ __align__(16) bf16 As[2][256 * 64];
  __shared__ __align__(16) bf16 Bs[2][BN * 64];

  // --- T1: bijective XCD-aware block swizzle (all grids here are %8==0) ---
  int id = blockIdx.x + gridDim.x * (blockIdx.y + gridDim.y * blockIdx.z);
  int nwg = gridDim.x * gridDim.y * gridDim.z;
  int sid = ((nwg & 7) == 0) ? ((id & 7) * (nwg >> 3) + (id >> 3)) : id;
  const int bx = sid % gridDim.x;
  const int by = (sid / gridDim.x) % gridDim.y;
  const int bz = sid / (gridDim.x * gridDim.y);

  const int tid = threadIdx.x;
  const long lK = K;
  const bf16* Ab = A + (long)bz * sAz + (long)by * 256 * lK;
  const bf16* Bb = B + (long)bz * sBz + (long)bx * BN * lK;

  const int w = tid >> 6, lane = tid & 63;
  const int wr = w >> 2, wc = w & 3;          // 2 x 4 wave grid
  const int l16 = lane & 15, quad = lane >> 4;

  // staging coords: thread -> (row srow within 64-row round, 16B slot sp)
  const int srow = tid >> 3;                  // 0..63
  const int sp = tid & 7;                     // physical slot
  // physical slot sp holds logical slot sp ^ (row & 7); row&7 == srow&7
  const int slog = (sp ^ (srow & 7)) << 3;    // element offset in source row

  // fragment read offsets (T2 swizzle): logical slot = kc*4+quad, row = l16&7
  const int pA0 = (quad ^ (l16 & 7)) << 3;    // kc = 0
  const int pA1 = pA0 ^ 32;                   // kc = 1 (slot ^ 4)

  auto stageA = [&](int buf, int kt) {
    const bf16* s = Ab + (long)kt * 64 + (long)srow * lK + slog;
    char* d = (char*)(&As[buf][0]) + tid * 16;
    #pragma unroll
    for (int r = 0; r < 4; ++r)
      gload16(s + (long)(r * 64) * lK, d + r * 8192);
  };
  auto stageB = [&](int buf, int kt) {
    const bf16* s = Bb + (long)kt * 64 + (long)srow * lK + slog;
    char* d = (char*)(&Bs[buf][0]) + tid * 16;
    #pragma unroll
    for (int r = 0; r < BROUNDS; ++r)
      gload16(s + (long)(r * 64) * lK, d + r * 8192);
  };

  floatx4 acc[8][NREP];
  #pragma unroll
  for (int m = 0; m < 8; ++m)
    #pragma unroll
    for (int n = 0; n < NREP; ++n) acc[m][n] = (floatx4)(0.0f);

  // prologue: tile 0 -> buf 0 (one-time cold cost)
  stageA(0, 0);
  stageB(0, 0);
  asm volatile("s_waitcnt vmcnt(0)" ::: "memory");
  __builtin_amdgcn_s_barrier();

  const int nk = K >> 6;
  int cur = 0;
  for (int t = 0; t < nk; ++t) {
    const bf16* __restrict__ Al = &As[cur][0];
    const bf16* __restrict__ Bl = &Bs[cur][0];
    const bool last = (t == nk - 1);
    short8 a[4];
    short8 b[2][NREP];
    #pragma unroll
    for (int p = 0; p < 4; ++p) {
      const int qm = p >> 1, kc = p & 1;
      const int poff = kc ? pA1 : pA0;
      // 4 A fragments for this (row-quadrant, k-chunk)
      #pragma unroll
      for (int i = 0; i < 4; ++i) {
        const int ar = wr * 128 + qm * 64 + i * 16 + l16;
        a[i] = *(const short8*)(Al + ar * 64 + poff);
      }
      // B fragments for this k-chunk, read once (reused at qm==1)
      if (qm == 0) {
        #pragma unroll
        for (int j = 0; j < NREP; ++j) {
          const int br = wc * (NREP * 16) + j * 16 + l16;
          b[kc][j] = *(const short8*)(Bl + br * 64 + poff);
        }
      }
      // issue next-tile staging early (phases 0,1) -> ~3 phases of cover
      if (!last) {
        if (p == 0) stageA(cur ^ 1, t + 1);
        if (p == 1) stageB(cur ^ 1, t + 1);
      }
      __builtin_amdgcn_s_barrier();
      __builtin_amdgcn_s_setprio(1);
      #pragma unroll
      for (int i = 0; i < 4; ++i)
        #pragma unroll
        for (int j = 0; j < NREP; ++j)
          acc[qm * 4 + i][j] = __builtin_amdgcn_mfma_f32_16x16x32_bf16(
              a[i], b[kc][j], acc[qm * 4 + i][j], 0, 0, 0);
      __builtin_amdgcn_s_setprio(0);
      if (p == 3) {
        // tile boundary: drain staging (issued >=2 phases ago), then barrier
        asm volatile("s_waitcnt vmcnt(0)" ::: "memory");
      }
      __builtin_amdgcn_s_barrier();
    }
    cur ^= 1;
  }

  // epilogue
  const int rbase = by * 256 + wr * 128 + quad * 4;
  const int cbase = bx * BN + wc * (NREP * 16) + l16;
  #pragma unroll
  for (int m = 0; m < 8; ++m) {
    const int row = rbase + m * 16;
    #pragma unroll
    for (int n = 0; n < NREP; ++n) {
      const int col = cbase + n * 16;
      floatx4 v = acc[m][n];
      if constexpr (MODE == 0) {
        bf16* C = (bf16*)Cv + (long)bz * sCz;
        const float bb = bias[col];
        #pragma unroll
        for (int r = 0; r < 4; ++r)
          C[(long)(row + r) * ldc + col] = __float2bfloat16(v[r] + bb);
      } else if constexpr (MODE == 1) {
        bf16* C = (bf16*)Cv + (long)bz * sCz;
        const float bb = bias[col];
        alignas(8) bf16 tmp[4];
        #pragma unroll
        for (int r = 0; r < 4; ++r) tmp[r] = __float2bfloat16(v[r] + bb);
        *(shortx4*)(C + (long)col * ldc + row) = *(const shortx4*)tmp;
      } else if constexpr (MODE == 2) {
        bf16* C = (bf16*)Cv + (long)bz * sCz;
        #pragma unroll
        for (int r = 0; r < 4; ++r)
          C[(long)(row + r) * ldc + col] = __float2bfloat16(v[r] * scale);
      } else {  // MODE 4
        float* C = (float*)Cv + (long)bz * sCz;
        const float bb = bias[col];
        floatx4 o_;
        #pragma unroll
        for (int r = 0; r < 4; ++r) o_[r] = v[r] + bb;
        *(floatx4*)(C + (long)col * ldc + row) = o_;
      }
    }
  }
}

// ---------------------------------------------------------------------------
// In-place row softmax over bf16 rows of length 4096. One block per row.
// ---------------------------------------------------------------------------
__global__ __launch_bounds__(256) void softmax_rows(bf16* __restrict__ sim) {
  bf16* p = sim + (long)blockIdx.y * ((long)SEQ * SEQ) + (long)blockIdx.x * SEQ;
  uint4* p4 = (uint4*)p;
  const int t = threadIdx.x;
  union U { uint4 u; ushort h[8]; } d[2];
  d[0].u = p4[t];
  d[1].u = p4[t + 256];
  float v[16];
  float mx = -3.0e38f;
  #pragma unroll
  for (int i = 0; i < 16; ++i) {
    v[i] = __uint_as_float(((unsigned)d[i >> 3].h[i & 7]) << 16);
    mx = fmaxf(mx, v[i]);
  }
  #pragma unroll
  for (int o = 32; o > 0; o >>= 1) mx = fmaxf(mx, __shfl_xor(mx, o));
  __shared__ float redmax[4], redsum[4];
  if ((t & 63) == 0) redmax[t >> 6] = mx;
  __syncthreads();
  mx = fmaxf(fmaxf(redmax[0], redmax[1]), fmaxf(redmax[2], redmax[3]));
  float sum = 0.f;
  #pragma unroll
  for (int i = 0; i < 16; ++i) {
    v[i] = __expf(v[i] - mx);
    sum += v[i];
  }
  #pragma unroll
  for (int o = 32; o > 0; o >>= 1) sum += __shfl_xor(sum, o);
  if ((t & 63) == 0) redsum[t >> 6] = sum;
  __syncthreads();
  sum = redsum[0] + redsum[1] + redsum[2] + redsum[3];
  const float inv = 1.0f / sum;
  union Hb { __hip_bfloat16 h; ushort u; };
  #pragma unroll
  for (int i = 0; i < 16; ++i) {
    Hb hb;
    hb.h = __float2bfloat16(v[i] * inv);
    d[i >> 3].h[i & 7] = hb.u;
  }
  p4[t] = d[0].u;
  p4[t + 256] = d[1].u;
}

// ---------------------------------------------------------------------------
extern "C" void kernel_launch(void* const* d_in, const int* in_sizes, int n_in,
                              void* d_out, int out_size, void* d_ws,
                              size_t ws_size, hipStream_t stream) {
  const float* q  = (const float*)d_in[0];
  const float* Wq = (const float*)d_in[1];
  const float* bq = (const float*)d_in[2];
  const float* Wk = (const float*)d_in[3];
  const float* bk = (const float*)d_in[4];
  const float* Wv = (const float*)d_in[5];
  const float* bv = (const float*)d_in[6];
  const float* Wo = (const float*)d_in[7];
  const float* bo = (const float*)d_in[8];
  float* out = (float*)d_out;

  bf16* ws = (bf16*)d_ws;
  const long WSZ = (long)DM * CH;         // 262144 elems per weight matrix
  const long XSZ = (long)SEQ * CH;        // 2097152 elems per batch
  const long SSZ = (long)SEQ * SEQ;       // 16777216 elems per batch
  bf16* Wqb = ws;
  bf16* Wkb = Wqb + WSZ;
  bf16* Wvb = Wqb + 2 * WSZ;
  bf16* Wob = Wqb + 3 * WSZ;
  bf16* xT  = Wqb + 4 * WSZ;
  bf16* Qb  = xT + BATCH * XSZ;
  bf16* Kb  = Qb + BATCH * XSZ;
  bf16* Vt  = Kb + BATCH * XSZ;   // (b, d, s) layout
  bf16* Ob  = Vt + BATCH * XSZ;
  bf16* Sim = Ob + BATCH * XSZ;   // (b, s, t) bf16, softmaxed in place

  cvt_weights<<<dim3(WSZ / 256, 4), 256, 0, stream>>>(Wq, Wk, Wv, Wo, ws);
  transpose_cvt<<<dim3(SEQ / 64, CH / 64, BATCH), 256, 0, stream>>>(q, xT);

  // Q = xT * Wq^T + bq  (4096x512x512), bf16 out, row-major [s][d]
  gemm_big<2, 0><<<dim3(4, 16, BATCH), 512, 0, stream>>>(
      xT, XSZ, Wqb, 0, Qb, XSZ, bq, 1.f, CH, DM);
  gemm_big<2, 0><<<dim3(4, 16, BATCH), 512, 0, stream>>>(
      xT, XSZ, Wkb, 0, Kb, XSZ, bk, 1.f, CH, DM);
  // V stored transposed: Vt[d][s]
  gemm_big<2, 1><<<dim3(4, 16, BATCH), 512, 0, stream>>>(
      xT, XSZ, Wvb, 0, Vt, XSZ, bv, 1.f, CH, SEQ);
  // sim = Q*K^T * scale (4096x4096x512): 256x256 tile
  gemm_big<4, 2><<<dim3(16, 16, BATCH), 512, 0, stream>>>(
      Qb, XSZ, Kb, XSZ, Sim, SSZ, nullptr, 0.04419417382415922f, CH, SEQ);
  softmax_rows<<<dim3(SEQ, BATCH), 256, 0, stream>>>(Sim);
  // o = P * V  (4096x512x4096): 256x128 tile, deep K
  gemm_big<2, 2><<<dim3(4, 16, BATCH), 512, 0, stream>>>(
      Sim, SSZ, Vt, XSZ, Ob, XSZ, nullptr, 1.0f, SEQ, DM);
  // y = o * Wo^T + bo, stored transposed into d_out as (b, c, s) fp32
  gemm_big<2, 4><<<dim3(4, 16, BATCH), 512, 0, stream>>>(
      Ob, XSZ, Wob, 0, out, XSZ, bo, 1.f, DM, SEQ);
}

// Round 3
// 357.120 us; speedup vs baseline: 1.2358x; 1.0700x over previous
//
#include <hip/hip_runtime.h>
#include <hip/hip_bf16.h>

typedef __hip_bfloat16 bf16;
typedef __attribute__((ext_vector_type(8))) short short8;
typedef __attribute__((ext_vector_type(4))) float floatx4;
typedef __attribute__((ext_vector_type(4))) short shortx4;

static constexpr int BATCH = 4;
static constexpr int CH    = 512;   // C
static constexpr int SEQ   = 4096;  // H*W
static constexpr int DM    = 512;   // model dim

__device__ __forceinline__ void gload16(const void* g, void* l) {
  __builtin_amdgcn_global_load_lds(
      (const __attribute__((address_space(1))) unsigned int*)g,
      (__attribute__((address_space(3))) unsigned int*)l,
      16, 0, 0);
}

// ---------------------------------------------------------------------------
// Weight fp32 -> bf16 conversion (4 matrices of 512x512)
// ---------------------------------------------------------------------------
__global__ __launch_bounds__(256) void cvt_weights(
    const float* __restrict__ w0, const float* __restrict__ w1,
    const float* __restrict__ w2, const float* __restrict__ w3,
    bf16* __restrict__ out) {
  const float* src = (blockIdx.y == 0) ? w0 : (blockIdx.y == 1) ? w1
                   : (blockIdx.y == 2) ? w2 : w3;
  int idx = blockIdx.x * 256 + threadIdx.x;
  out[(long)blockIdx.y * (DM * CH) + idx] = __float2bfloat16(src[idx]);
}

// ---------------------------------------------------------------------------
// x (b,c,s) fp32 -> xT (b,s,c) bf16, 64x64 LDS tiles
// ---------------------------------------------------------------------------
__global__ __launch_bounds__(256) void transpose_cvt(
    const float* __restrict__ x, bf16* __restrict__ xT) {
  __shared__ float tile[64][65];
  const int s0 = blockIdx.x * 64, c0 = blockIdx.y * 64;
  const float* xb = x + (long)blockIdx.z * CH * SEQ;
  bf16* xTb = xT + (long)blockIdx.z * SEQ * CH;
  const int t = threadIdx.x;
  const int sl = t & 63, cq = t >> 6;
  #pragma unroll
  for (int i = 0; i < 16; ++i) {
    int cl = cq * 16 + i;
    tile[cl][sl] = xb[(long)(c0 + cl) * SEQ + s0 + sl];
  }
  __syncthreads();
  const int cl2 = t & 63, sq = t >> 6;
  #pragma unroll
  for (int i = 0; i < 16; ++i) {
    int sl2 = sq * 16 + i;
    xTb[(long)(s0 + sl2) * CH + c0 + cl2] = __float2bfloat16(tile[cl2][sl2]);
  }
}

// ---------------------------------------------------------------------------
// gemm_big (BN=256 path, used for QK^T only): 256x256 tile, BK=64, 8 waves
// 2Mx4N, per-wave 128x64. 4 balanced phases/K-tile, double-buffered LDS,
// T1 XCD swizzle, T2 XOR swizzle, raw barriers, T5 setprio, one vmcnt(0)
// drain per K-tile. MODE 2: bf16 out = acc*scale, row-major.
// ---------------------------------------------------------------------------
template <int NREP, int MODE>
__global__ __launch_bounds__(512, 2) void gemm_big(
    const bf16* __restrict__ A, long sAz,
    const bf16* __restrict__ B, long sBz,
    void* __restrict__ Cv, long sCz,
    const float* __restrict__ bias, float scale,
    int K, int ldc) {
  constexpr int BN = NREP * 64;
  constexpr int BROUNDS = BN / 64;
  __shared__ __align__(16) bf16 As[2][256 * 64];
  __shared__ __align__(16) bf16 Bs[2][BN * 64];

  int id = blockIdx.x + gridDim.x * (blockIdx.y + gridDim.y * blockIdx.z);
  int nwg = gridDim.x * gridDim.y * gridDim.z;
  int sid = ((nwg & 7) == 0) ? ((id & 7) * (nwg >> 3) + (id >> 3)) : id;
  const int bx = sid % gridDim.x;
  const int by = (sid / gridDim.x) % gridDim.y;
  const int bz = sid / (gridDim.x * gridDim.y);

  const int tid = threadIdx.x;
  const long lK = K;
  const bf16* Ab = A + (long)bz * sAz + (long)by * 256 * lK;
  const bf16* Bb = B + (long)bz * sBz + (long)bx * BN * lK;

  const int w = tid >> 6, lane = tid & 63;
  const int wr = w >> 2, wc = w & 3;          // 2 x 4 wave grid
  const int l16 = lane & 15, quad = lane >> 4;

  const int srow = tid >> 3;
  const int sp = tid & 7;
  const int slog = (sp ^ (srow & 7)) << 3;

  const int pA0 = (quad ^ (l16 & 7)) << 3;
  const int pA1 = pA0 ^ 32;

  auto stageA = [&](int buf, int kt) {
    const bf16* s = Ab + (long)kt * 64 + (long)srow * lK + slog;
    char* d = (char*)(&As[buf][0]) + tid * 16;
    #pragma unroll
    for (int r = 0; r < 4; ++r)
      gload16(s + (long)(r * 64) * lK, d + r * 8192);
  };
  auto stageB = [&](int buf, int kt) {
    const bf16* s = Bb + (long)kt * 64 + (long)srow * lK + slog;
    char* d = (char*)(&Bs[buf][0]) + tid * 16;
    #pragma unroll
    for (int r = 0; r < BROUNDS; ++r)
      gload16(s + (long)(r * 64) * lK, d + r * 8192);
  };

  floatx4 acc[8][NREP];
  #pragma unroll
  for (int m = 0; m < 8; ++m)
    #pragma unroll
    for (int n = 0; n < NREP; ++n) acc[m][n] = (floatx4)(0.0f);

  stageA(0, 0);
  stageB(0, 0);
  asm volatile("s_waitcnt vmcnt(0)" ::: "memory");
  __builtin_amdgcn_s_barrier();

  const int nk = K >> 6;
  int cur = 0;
  for (int t = 0; t < nk; ++t) {
    const bf16* __restrict__ Al = &As[cur][0];
    const bf16* __restrict__ Bl = &Bs[cur][0];
    const bool last = (t == nk - 1);
    short8 a[4];
    short8 b[2][NREP];
    #pragma unroll
    for (int p = 0; p < 4; ++p) {
      const int qm = p >> 1, kc = p & 1;
      const int poff = kc ? pA1 : pA0;
      #pragma unroll
      for (int i = 0; i < 4; ++i) {
        const int ar = wr * 128 + qm * 64 + i * 16 + l16;
        a[i] = *(const short8*)(Al + ar * 64 + poff);
      }
      if (qm == 0) {
        #pragma unroll
        for (int j = 0; j < NREP; ++j) {
          const int br = wc * (NREP * 16) + j * 16 + l16;
          b[kc][j] = *(const short8*)(Bl + br * 64 + poff);
        }
      }
      if (!last) {
        if (p == 0) stageA(cur ^ 1, t + 1);
        if (p == 1) stageB(cur ^ 1, t + 1);
      }
      __builtin_amdgcn_s_barrier();
      __builtin_amdgcn_s_setprio(1);
      #pragma unroll
      for (int i = 0; i < 4; ++i)
        #pragma unroll
        for (int j = 0; j < NREP; ++j)
          acc[qm * 4 + i][j] = __builtin_amdgcn_mfma_f32_16x16x32_bf16(
              a[i], b[kc][j], acc[qm * 4 + i][j], 0, 0, 0);
      __builtin_amdgcn_s_setprio(0);
      if (p == 3) {
        asm volatile("s_waitcnt vmcnt(0)" ::: "memory");
      }
      __builtin_amdgcn_s_barrier();
    }
    cur ^= 1;
  }

  const int rbase = by * 256 + wr * 128 + quad * 4;
  const int cbase = bx * BN + wc * (NREP * 16) + l16;
  #pragma unroll
  for (int m = 0; m < 8; ++m) {
    const int row = rbase + m * 16;
    #pragma unroll
    for (int n = 0; n < NREP; ++n) {
      const int col = cbase + n * 16;
      floatx4 v = acc[m][n];
      if constexpr (MODE == 2) {
        bf16* C = (bf16*)Cv + (long)bz * sCz;
        #pragma unroll
        for (int r = 0; r < 4; ++r)
          C[(long)(row + r) * ldc + col] = __float2bfloat16(v[r] * scale);
      }
    }
  }
}

// ---------------------------------------------------------------------------
// gemm_bn128: 256x128 tile, BK=64, 8 waves in 4Mx2N grid, per-wave 64x64.
// 2 phases per K-tile (one per K=32 chunk): each phase = 8 ds_read_b128 +
// 16 MFMA (m201's proven mix; half the barriers of the old 4-phase path).
// TRIPLE-buffered LDS (144 KB) + counted vmcnt: stage tile t+2 during tile
// t, tile boundary waits vmcnt(6) (never 0 in steady state) -> each tile's
// loads get a full tile of cover. T1 XCD swizzle, T2 XOR swizzle, T5.
// MODE 0: bf16 = acc + bias[col], C[row*ldc+col]
// MODE 1: bf16 = acc + bias[col], transposed C[col*ldc+row]
// MODE 2: bf16 = acc * scale,     C[row*ldc+col]
// MODE 4: f32  = acc + bias[col], transposed C[col*ldc+row]
// Requires: M % 256 == 0, N % 128 == 0, K % 64 == 0, K >= 256.
// ---------------------------------------------------------------------------
template <int MODE>
__global__ __launch_bounds__(512, 2) void gemm_bn128(
    const bf16* __restrict__ A, long sAz,
    const bf16* __restrict__ B, long sBz,
    void* __restrict__ Cv, long sCz,
    const float* __restrict__ bias, float scale,
    int K, int ldc) {
  __shared__ __align__(16) bf16 As[3][256 * 64];
  __shared__ __align__(16) bf16 Bs[3][128 * 64];

  int id = blockIdx.x + gridDim.x * (blockIdx.y + gridDim.y * blockIdx.z);
  int nwg = gridDim.x * gridDim.y * gridDim.z;
  int sid = ((nwg & 7) == 0) ? ((id & 7) * (nwg >> 3) + (id >> 3)) : id;
  const int bx = sid % gridDim.x;
  const int by = (sid / gridDim.x) % gridDim.y;
  const int bz = sid / (gridDim.x * gridDim.y);

  const int tid = threadIdx.x;
  const long lK = K;
  const bf16* Ab = A + (long)bz * sAz + (long)by * 256 * lK;
  const bf16* Bb = B + (long)bz * sBz + (long)bx * 128 * lK;

  const int w = tid >> 6, lane = tid & 63;
  const int wr = w >> 1, wc = w & 1;          // 4 x 2 wave grid
  const int l16 = lane & 15, quad = lane >> 4;

  // staging: thread -> (row within 64-row round, physical 16B slot)
  const int srow = tid >> 3;
  const int sp = tid & 7;
  const int slog = (sp ^ (srow & 7)) << 3;    // pre-swizzled source column

  // fragment read offsets: logical slot = kc*4+quad, row parity = l16&7
  const int pA0 = (quad ^ (l16 & 7)) << 3;
  const int pA1 = pA0 ^ 32;

  auto stageA = [&](int buf, int kt) {
    const bf16* s = Ab + (long)kt * 64 + (long)srow * lK + slog;
    char* d = (char*)(&As[buf][0]) + tid * 16;
    #pragma unroll
    for (int r = 0; r < 4; ++r)
      gload16(s + (long)(r * 64) * lK, d + r * 8192);
  };
  auto stageB = [&](int buf, int kt) {
    const bf16* s = Bb + (long)kt * 64 + (long)srow * lK + slog;
    char* d = (char*)(&Bs[buf][0]) + tid * 16;
    #pragma unroll
    for (int r = 0; r < 2; ++r)
      gload16(s + (long)(r * 64) * lK, d + r * 8192);
  };

  floatx4 acc[4][4];
  #pragma unroll
  for (int m = 0; m < 4; ++m)
    #pragma unroll
    for (int n = 0; n < 4; ++n) acc[m][n] = (floatx4)(0.0f);

  const int nk = K >> 6;
  // prologue: stage tiles 0 and 1 (12 gloads); wait for tile 0 (6 oldest)
  stageA(0, 0); stageB(0, 0);
  stageA(1, 1); stageB(1, 1);
  asm volatile("s_waitcnt vmcnt(6)" ::: "memory");
  __builtin_amdgcn_s_barrier();

  int bcur = 0, bstage = 2;
  for (int t = 0; t < nk; ++t) {
    const bf16* __restrict__ Al = &As[bcur][0];
    const bf16* __restrict__ Bl = &Bs[bcur][0];
    const bool more = (t + 2 < nk);
    #pragma unroll
    for (int kc = 0; kc < 2; ++kc) {
      const int poff = kc ? pA1 : pA0;
      short8 a[4], b[4];
      #pragma unroll
      for (int i = 0; i < 4; ++i)
        a[i] = *(const short8*)(Al + (wr * 64 + i * 16 + l16) * 64 + poff);
      #pragma unroll
      for (int j = 0; j < 4; ++j)
        b[j] = *(const short8*)(Bl + (wc * 64 + j * 16 + l16) * 64 + poff);
      if (more) {
        if (kc == 0) stageA(bstage, t + 2);
        else         stageB(bstage, t + 2);
      }
      __builtin_amdgcn_s_barrier();
      __builtin_amdgcn_s_setprio(1);
      #pragma unroll
      for (int i = 0; i < 4; ++i)
        #pragma unroll
        for (int j = 0; j < 4; ++j)
          acc[i][j] = __builtin_amdgcn_mfma_f32_16x16x32_bf16(
              a[i], b[j], acc[i][j], 0, 0, 0);
      __builtin_amdgcn_s_setprio(0);
      if (kc == 1) {
        // tile boundary: counted wait -> tile t+1 landed, t+2 stays in flight
        if (more)            asm volatile("s_waitcnt vmcnt(6)" ::: "memory");
        else if (t + 1 < nk) asm volatile("s_waitcnt vmcnt(0)" ::: "memory");
      }
      __builtin_amdgcn_s_barrier();
    }
    bcur = (bcur == 2) ? 0 : bcur + 1;
    bstage = (bstage == 2) ? 0 : bstage + 1;
  }

  // epilogue: per-wave 64x64 block, frag (m,n): rows +quad*4, cols +l16
  const int rbase = by * 256 + wr * 64 + quad * 4;
  const int cbase = bx * 128 + wc * 64 + l16;
  #pragma unroll
  for (int m = 0; m < 4; ++m) {
    const int row = rbase + m * 16;
    #pragma unroll
    for (int n = 0; n < 4; ++n) {
      const int col = cbase + n * 16;
      floatx4 v = acc[m][n];
      if constexpr (MODE == 0) {
        bf16* C = (bf16*)Cv + (long)bz * sCz;
        const float bb = bias[col];
        #pragma unroll
        for (int r = 0; r < 4; ++r)
          C[(long)(row + r) * ldc + col] = __float2bfloat16(v[r] + bb);
      } else if constexpr (MODE == 1) {
        bf16* C = (bf16*)Cv + (long)bz * sCz;
        const float bb = bias[col];
        alignas(8) bf16 tmp[4];
        #pragma unroll
        for (int r = 0; r < 4; ++r) tmp[r] = __float2bfloat16(v[r] + bb);
        *(shortx4*)(C + (long)col * ldc + row) = *(const shortx4*)tmp;
      } else if constexpr (MODE == 2) {
        bf16* C = (bf16*)Cv + (long)bz * sCz;
        #pragma unroll
        for (int r = 0; r < 4; ++r)
          C[(long)(row + r) * ldc + col] = __float2bfloat16(v[r] * scale);
      } else {  // MODE 4
        float* C = (float*)Cv + (long)bz * sCz;
        const float bb = bias[col];
        floatx4 o_;
        #pragma unroll
        for (int r = 0; r < 4; ++r) o_[r] = v[r] + bb;
        *(floatx4*)(C + (long)col * ldc + row) = o_;
      }
    }
  }
}

// ---------------------------------------------------------------------------
// In-place row softmax over bf16 rows of length 4096. One block per row.
// ---------------------------------------------------------------------------
__global__ __launch_bounds__(256) void softmax_rows(bf16* __restrict__ sim) {
  bf16* p = sim + (long)blockIdx.y * ((long)SEQ * SEQ) + (long)blockIdx.x * SEQ;
  uint4* p4 = (uint4*)p;
  const int t = threadIdx.x;
  union U { uint4 u; ushort h[8]; } d[2];
  d[0].u = p4[t];
  d[1].u = p4[t + 256];
  float v[16];
  float mx = -3.0e38f;
  #pragma unroll
  for (int i = 0; i < 16; ++i) {
    v[i] = __uint_as_float(((unsigned)d[i >> 3].h[i & 7]) << 16);
    mx = fmaxf(mx, v[i]);
  }
  #pragma unroll
  for (int o = 32; o > 0; o >>= 1) mx = fmaxf(mx, __shfl_xor(mx, o));
  __shared__ float redmax[4], redsum[4];
  if ((t & 63) == 0) redmax[t >> 6] = mx;
  __syncthreads();
  mx = fmaxf(fmaxf(redmax[0], redmax[1]), fmaxf(redmax[2], redmax[3]));
  float sum = 0.f;
  #pragma unroll
  for (int i = 0; i < 16; ++i) {
    v[i] = __expf(v[i] - mx);
    sum += v[i];
  }
  #pragma unroll
  for (int o = 32; o > 0; o >>= 1) sum += __shfl_xor(sum, o);
  if ((t & 63) == 0) redsum[t >> 6] = sum;
  __syncthreads();
  sum = redsum[0] + redsum[1] + redsum[2] + redsum[3];
  const float inv = 1.0f / sum;
  union Hb { __hip_bfloat16 h; ushort u; };
  #pragma unroll
  for (int i = 0; i < 16; ++i) {
    Hb hb;
    hb.h = __float2bfloat16(v[i] * inv);
    d[i >> 3].h[i & 7] = hb.u;
  }
  p4[t] = d[0].u;
  p4[t + 256] = d[1].u;
}

// ---------------------------------------------------------------------------
extern "C" void kernel_launch(void* const* d_in, const int* in_sizes, int n_in,
                              void* d_out, int out_size, void* d_ws,
                              size_t ws_size, hipStream_t stream) {
  const float* q  = (const float*)d_in[0];
  const float* Wq = (const float*)d_in[1];
  const float* bq = (const float*)d_in[2];
  const float* Wk = (const float*)d_in[3];
  const float* bk = (const float*)d_in[4];
  const float* Wv = (const float*)d_in[5];
  const float* bv = (const float*)d_in[6];
  const float* Wo = (const float*)d_in[7];
  const float* bo = (const float*)d_in[8];
  float* out = (float*)d_out;

  bf16* ws = (bf16*)d_ws;
  const long WSZ = (long)DM * CH;         // 262144 elems per weight matrix
  const long XSZ = (long)SEQ * CH;        // 2097152 elems per batch
  const long SSZ = (long)SEQ * SEQ;       // 16777216 elems per batch
  bf16* Wqb = ws;
  bf16* Wkb = Wqb + WSZ;
  bf16* Wvb = Wqb + 2 * WSZ;
  bf16* Wob = Wqb + 3 * WSZ;
  bf16* xT  = Wqb + 4 * WSZ;
  bf16* Qb  = xT + BATCH * XSZ;
  bf16* Kb  = Qb + BATCH * XSZ;
  bf16* Vt  = Kb + BATCH * XSZ;   // (b, d, s) layout
  bf16* Ob  = Vt + BATCH * XSZ;
  bf16* Sim = Ob + BATCH * XSZ;   // (b, s, t) bf16, softmaxed in place

  cvt_weights<<<dim3(WSZ / 256, 4), 256, 0, stream>>>(Wq, Wk, Wv, Wo, ws);
  transpose_cvt<<<dim3(SEQ / 64, CH / 64, BATCH), 256, 0, stream>>>(q, xT);

  // Q = xT * Wq^T + bq  (4096x512x512), bf16 out, row-major [s][d]
  gemm_bn128<0><<<dim3(4, 16, BATCH), 512, 0, stream>>>(
      xT, XSZ, Wqb, 0, Qb, XSZ, bq, 1.f, CH, DM);
  gemm_bn128<0><<<dim3(4, 16, BATCH), 512, 0, stream>>>(
      xT, XSZ, Wkb, 0, Kb, XSZ, bk, 1.f, CH, DM);
  // V stored transposed: Vt[d][s]
  gemm_bn128<1><<<dim3(4, 16, BATCH), 512, 0, stream>>>(
      xT, XSZ, Wvb, 0, Vt, XSZ, bv, 1.f, CH, SEQ);
  // sim = Q*K^T * scale (4096x4096x512): 256x256 tile
  gemm_big<4, 2><<<dim3(16, 16, BATCH), 512, 0, stream>>>(
      Qb, XSZ, Kb, XSZ, Sim, SSZ, nullptr, 0.04419417382415922f, CH, SEQ);
  softmax_rows<<<dim3(SEQ, BATCH), 256, 0, stream>>>(Sim);
  // o = P * V  (4096x512x4096): 256x128 tile, deep K, triple-buffered
  gemm_bn128<2><<<dim3(4, 16, BATCH), 512, 0, stream>>>(
      Sim, SSZ, Vt, XSZ, Ob, XSZ, nullptr, 1.0f, SEQ, DM);
  // y = o * Wo^T + bo, stored transposed into d_out as (b, c, s) fp32
  gemm_bn128<4><<<dim3(4, 16, BATCH), 512, 0, stream>>>(
      Ob, XSZ, Wob, 0, out, XSZ, bo, 1.f, DM, SEQ);
}